// Round 12
// baseline (851.731 us; speedup 1.0000x reference)
//
#include <hip/hip_runtime.h>
#include <math.h>

// ToxicityGATv2 — round 21: gemm kb-loop restructured to ping-pong B staging.
//  * B chunk k+1 global-loaded into 4xuint4 regs before MFMA on chunk k, then
//    written to the other LDS half; ONE barrier per chunk (5 total vs 9 full
//    vm/lgkm-drain barriers). Load latency hides under MFMA.
//  * b_s pad 40 -> 36 shorts (2-way bank aliasing only; also shrinks LDS).
//    LDS 37888 -> 54272 B: still 3 blocks/CU (= the 782/256 residency needed).
// Everything else = round 20 (779.6us best: bf16 buf+xn, drainless epilogue).

constexpr int N_ = 50000;
constexpr int E_ = 400000;
constexpr int G_ = 2000;
constexpr int H_ = 128;
constexpr int IN_ = 39;

constexpr int HIST_B = 1024;
constexpr int GOFF_B = (N_ + 255) / 256;      // 196
constexpr int PACK_B = 384;
constexpr int INGEMM_B = (N_ + 31) / 32;      // 1563

typedef __attribute__((ext_vector_type(8))) short bf16x8;
typedef __attribute__((ext_vector_type(4))) float f32x4;

// ---------------- bf16 pack/unpack (RNE) ----------------
__device__ __forceinline__ unsigned pk_bf16(float a, float b) {
  unsigned ua = __float_as_uint(a);
  unsigned ub = __float_as_uint(b);
  ua = (ua + 0x7fffu + ((ua >> 16) & 1u)) >> 16;
  ub = (ub + 0x7fffu + ((ub >> 16) & 1u)) & 0xffff0000u;
  return ua | ub;
}
__device__ __forceinline__ unsigned short bf16_1(float x) {
  unsigned u = __float_as_uint(x);
  u = (u + 0x7fffu + ((u >> 16) & 1u)) >> 16;
  return (unsigned short)u;
}
__device__ __forceinline__ float up_lo(unsigned u) { return __uint_as_float(u << 16); }
__device__ __forceinline__ float up_hi(unsigned u) { return __uint_as_float(u & 0xffff0000u); }
__device__ __forceinline__ float up_s(unsigned short s) {
  return __uint_as_float(((unsigned)s) << 16);
}

// ---------------- DPP rotate-reduce over 16-lane rows (VALU pipe, no LDS) ----
template <int CTRL>
__device__ __forceinline__ float dpp_radd(float x) {
  int y = __builtin_amdgcn_update_dpp(0, __float_as_int(x), CTRL, 0xF, 0xF, false);
  return x + __int_as_float(y);
}
__device__ __forceinline__ float row_reduce16(float p) {
  p = dpp_radd<0x121>(p);  // row_ror:1
  p = dpp_radd<0x122>(p);  // row_ror:2
  p = dpp_radd<0x124>(p);  // row_ror:4
  p = dpp_radd<0x128>(p);  // row_ror:8
  return p;
}

// ---------------- merged prep: hist | goff | pack_weights | in_gemm ----------
__global__ __launch_bounds__(256) void prep_kernel(const int* __restrict__ ei,
                                                   const int* __restrict__ batch,
                                                   const float* __restrict__ Wl,
                                                   const float* __restrict__ Wr,
                                                   const float* __restrict__ x,
                                                   const float* __restrict__ in_W,
                                                   const float* __restrict__ in_b,
                                                   int* __restrict__ deg,
                                                   int* __restrict__ goff,
                                                   unsigned short* __restrict__ wpack,
                                                   unsigned short* __restrict__ yb,
                                                   float* __restrict__ ssum,
                                                   float* __restrict__ ssq) {
  int b = blockIdx.x;
  int t = threadIdx.x;
  if (b < HIST_B) {
    for (int i = b * 256 + t; i < E_; i += HIST_B * 256)
      atomicAdd(&deg[ei[E_ + i]], 1);
    return;
  }
  b -= HIST_B;
  if (b < GOFF_B) {
    int i = b * 256 + t;
    if (i >= N_) return;
    int bi = batch[i];
    int bp = (i == 0) ? -1 : batch[i - 1];
    for (int g = bp + 1; g <= bi; g++) goff[g] = i;
    if (i == N_ - 1) {
      for (int g = bi + 1; g <= G_; g++) goff[g] = N_;
    }
    return;
  }
  b -= GOFF_B;
  if (b < PACK_B) {
    int i = b * 256 + t;
    if (i >= 3 * 128 * 256) return;
    int l = i >> 15;
    int rem = i & 32767;
    int k = rem >> 8;
    int n = rem & 255;
    const float* Wsrc = (n < 128) ? (Wl + l * H_ * H_) : (Wr + l * H_ * H_);
    int nn = n & 127;
    wpack[(size_t)l * 32768 + n * 128 + k] = bf16_1(Wsrc[k * H_ + nn]);
    return;
  }
  b -= PACK_B;
  // ---- in_gemm body (bf16 output) ----
  __shared__ float xs[32][40];
  __shared__ float s1[256], s2[256];
  int row0 = b * 32;
  for (int i = t; i < 32 * IN_; i += 256) {
    int r = i / IN_, k = i % IN_;
    int row = row0 + r;
    xs[r][k] = (row < N_) ? x[row * IN_ + k] : 0.f;
  }
  __syncthreads();
  int col = t & 127;
  int half = t >> 7;
  float acc[16];
#pragma unroll
  for (int r = 0; r < 16; r++) acc[r] = 0.f;
  for (int k = 0; k < IN_; k++) {
    float w = in_W[k * H_ + col];
#pragma unroll
    for (int r = 0; r < 16; r++) acc[r] = fmaf(xs[half * 16 + r][k], w, acc[r]);
  }
  float bb = in_b[col];
  float a1 = 0.f, a2 = 0.f;
#pragma unroll
  for (int r = 0; r < 16; r++) {
    int row = row0 + half * 16 + r;
    float v = acc[r] + bb;
    if (row < N_) {
      yb[(size_t)row * H_ + col] = bf16_1(v);
      a1 += v;
      a2 = fmaf(v, v, a2);
    }
  }
  s1[t] = a1; s2[t] = a2;
  __syncthreads();
  if (t < 128) {
    atomicAdd(&ssum[t], s1[t] + s1[t + 128]);
    atomicAdd(&ssq[t], s2[t] + s2[t + 128]);
  }
}

// ---------------- single-pass chained scan (49 co-resident blocks) ----------
__global__ __launch_bounds__(1024) void scan_onepass(const int* __restrict__ deg,
                                                     int* __restrict__ eoff,
                                                     int* __restrict__ cursor,
                                                     int* __restrict__ pref, int n) {
  __shared__ int wsum[16];
  __shared__ int sbase;
  int t = threadIdx.x, lane = t & 63, wid = t >> 6;
  int b = blockIdx.x;
  int idx = b * 1024 + t;
  int v = (idx < n) ? deg[idx] : 0;
  int x = v;
#pragma unroll
  for (int off = 1; off < 64; off <<= 1) {
    int y = __shfl_up(x, off, 64);
    if (lane >= off) x += y;
  }
  if (lane == 63) wsum[wid] = x;
  __syncthreads();
  if (t == 0) {
    int acc = 0;
#pragma unroll
    for (int w = 0; w < 16; w++) { int tmp = wsum[w]; wsum[w] = acc; acc += tmp; }
    int prev = 0;
    if (b > 0) {
      int got;
      do { got = atomicAdd(&pref[b - 1], 0); } while (got == 0);  // +1 sentinel
      prev = got - 1;
    }
    atomicExch(&pref[b], prev + acc + 1);
    sbase = prev;
  }
  __syncthreads();
  if (idx < n) {
    int e = sbase + wsum[wid] + x - v;
    eoff[idx] = e;
    cursor[idx] = e;
    if (idx == n - 1) eoff[n] = E_;
  }
}

// ---------------- edge scatter (bf16 attrs) ----------------
__global__ __launch_bounds__(256) void edge_scatter(const int* __restrict__ ei,
                                                    const float* __restrict__ ea,
                                                    int* __restrict__ cursor,
                                                    int* __restrict__ esrc,
                                                    unsigned* __restrict__ easb) {
  int e = blockIdx.x * 256 + threadIdx.x;
  if (e >= E_) return;
  int src = ei[e];
  int dst = ei[E_ + e];
  int j = atomicAdd(&cursor[dst], 1);
  esrc[j] = src;
  const float4* eav = (const float4*)(ea + (size_t)e * 8);
  float4 a0 = eav[0], a1 = eav[1];
  uint4 o;
  o.x = pk_bf16(a0.x, a0.y);
  o.y = pk_bf16(a0.z, a0.w);
  o.z = pk_bf16(a1.x, a1.y);
  o.w = pk_bf16(a1.z, a1.w);
  ((uint4*)easb)[j] = o;
}

// ---------------- MFMA node GEMM (ping-pong B, bf16 buf + bf16 xn) ----------
// MODE 1: v=relu(bn(buf)); xn=v.  MODE 2: v=xn+elu(bn(buf)); xn=v.
template <int MODE>
__global__ __launch_bounds__(256) void gemm_mfma(unsigned short* __restrict__ xnb,
                                                 const unsigned short* __restrict__ bufs,
                                                 const float* __restrict__ g,
                                                 const float* __restrict__ beta,
                                                 const float* __restrict__ ssum,
                                                 const float* __restrict__ ssq,
                                                 float rows_inv,
                                                 const unsigned short* __restrict__ wp,
                                                 unsigned* __restrict__ xlb,
                                                 unsigned* __restrict__ xrb) {
  __shared__ char smem[17408 + 2 * 18432];
  short (*a_s)[136] = (short(*)[136])smem;                    // 64 rows x 128 k (pad 136)
  short (*b_s0)[36] = (short(*)[36])(smem + 17408);           // 256 n x 32 k (pad 36)
  short (*b_s1)[36] = (short(*)[36])(smem + 17408 + 18432);
  float* t2base = (float*)(smem + 17408);                     // epilogue reuse
  int t = threadIdx.x;
  int lane = t & 63, w = t >> 6;
  int quad = lane >> 4, lc = lane & 15;
  int row0 = blockIdx.x * 64;
  int nb0 = t >> 2;             // B-staging row base (+64 per j)
  int kb8 = (t & 3) * 8;        // B-staging k8 offset (constant per thread)

  // ---- stage A (fused BN epilogue, bf16 xn updated, bf16 into LDS) ----
  {
    int r = t >> 2;
    int row = row0 + r;
    int kb0 = (t & 3) * 32;
    bool valid = row < N_;
    for (int kk = 0; kk < 32; kk += 4) {
      int c = kb0 + kk;
      float4 v = make_float4(0.f, 0.f, 0.f, 0.f);
      uint2 pk;
      if (valid) {
        uint2 bp = *(const uint2*)&bufs[(size_t)row * H_ + c];
        float bx = up_lo(bp.x), by = up_hi(bp.x), bz = up_lo(bp.y), bw = up_hi(bp.y);
        float4 gv = *(const float4*)&g[c];
        float4 be = *(const float4*)&beta[c];
        float4 s1 = *(const float4*)&ssum[c];
        float4 s2 = *(const float4*)&ssq[c];
        float m0 = s1.x * rows_inv, m1 = s1.y * rows_inv, m2 = s1.z * rows_inv, m3 = s1.w * rows_inv;
        float r0 = rsqrtf(s2.x * rows_inv - m0 * m0 + 1e-5f);
        float r1 = rsqrtf(s2.y * rows_inv - m1 * m1 + 1e-5f);
        float r2 = rsqrtf(s2.z * rows_inv - m2 * m2 + 1e-5f);
        float r3 = rsqrtf(s2.w * rows_inv - m3 * m3 + 1e-5f);
        float t0 = gv.x * (bx - m0) * r0 + be.x;
        float t1 = gv.y * (by - m1) * r1 + be.y;
        float t2 = gv.z * (bz - m2) * r2 + be.z;
        float t3 = gv.w * (bw - m3) * r3 + be.w;
        if (MODE == 1) {
          v = make_float4(fmaxf(t0, 0.f), fmaxf(t1, 0.f), fmaxf(t2, 0.f), fmaxf(t3, 0.f));
        } else {
          uint2 xo = *(const uint2*)&xnb[(size_t)row * H_ + c];
          float x0 = up_lo(xo.x), x1 = up_hi(xo.x), x2 = up_lo(xo.y), x3 = up_hi(xo.y);
          v.x = x0 + ((t0 > 0.f) ? t0 : (__expf(t0) - 1.f));
          v.y = x1 + ((t1 > 0.f) ? t1 : (__expf(t1) - 1.f));
          v.z = x2 + ((t2 > 0.f) ? t2 : (__expf(t2) - 1.f));
          v.w = x3 + ((t3 > 0.f) ? t3 : (__expf(t3) - 1.f));
        }
        pk.x = pk_bf16(v.x, v.y);
        pk.y = pk_bf16(v.z, v.w);
        *(uint2*)&xnb[(size_t)row * H_ + c] = pk;
      } else {
        pk.x = 0; pk.y = 0;
      }
      *(uint2*)&a_s[r][c] = pk;
    }
  }

  f32x4 acc[16];
#pragma unroll
  for (int nt = 0; nt < 16; nt++) acc[nt] = (f32x4){0.f, 0.f, 0.f, 0.f};

  // ---- ping-pong B staging: one barrier per kb chunk ----
  uint4 br0, br1, br2, br3;
#define LOADB(kb)                                                              \
  br0 = *(const uint4*)&wp[(size_t)nb0 * 128 + (kb) * 32 + kb8];               \
  br1 = *(const uint4*)&wp[(size_t)(nb0 + 64) * 128 + (kb) * 32 + kb8];        \
  br2 = *(const uint4*)&wp[(size_t)(nb0 + 128) * 128 + (kb) * 32 + kb8];       \
  br3 = *(const uint4*)&wp[(size_t)(nb0 + 192) * 128 + (kb) * 32 + kb8];
#define STOREB(bs)                                                             \
  *(uint4*)&bs[nb0][kb8] = br0;                                                \
  *(uint4*)&bs[nb0 + 64][kb8] = br1;                                           \
  *(uint4*)&bs[nb0 + 128][kb8] = br2;                                          \
  *(uint4*)&bs[nb0 + 192][kb8] = br3;

  LOADB(0);
  STOREB(b_s0);
  __syncthreads();
#pragma unroll
  for (int kb = 0; kb < 4; kb++) {
    if (kb < 3) { LOADB(kb + 1); }
    short (*bs)[36] = (kb & 1) ? b_s1 : b_s0;
    bf16x8 av = *(const bf16x8*)&a_s[w * 16 + lc][kb * 32 + quad * 8];
#pragma unroll
    for (int nt = 0; nt < 16; nt++) {
      bf16x8 bv = *(const bf16x8*)&bs[nt * 16 + lc][quad * 8];
      acc[nt] = __builtin_amdgcn_mfma_f32_16x16x32_bf16(av, bv, acc[nt], 0, 0, 0);
    }
    if (kb < 3) {
      short (*bsn)[36] = (kb & 1) ? b_s0 : b_s1;
      STOREB(bsn);
    }
    __syncthreads();
  }
#undef LOADB
#undef STOREB

  // ---- epilogue: transpose 16x32 chunks via LDS, packed coalesced stores ----
  // (drainless per r20: t2 is wave-private, DS ops in-order per wave)
  float* t2 = t2base + w * 544;  // 16 rows x 34 cols fp32, per-wave private
  for (int ntp = 0; ntp < 8; ntp++) {
#pragma unroll
    for (int rr = 0; rr < 4; rr++) {
      t2[(quad * 4 + rr) * 34 + lc] = acc[2 * ntp][rr];
      t2[(quad * 4 + rr) * 34 + 16 + lc] = acc[2 * ntp + 1][rr];
    }
#pragma unroll
    for (int it = 0; it < 4; it++) {
      int item = lane + it * 64;
      int p = item & 15, rowi = item >> 4;
      float v0 = t2[rowi * 34 + 2 * p];
      float v1 = t2[rowi * 34 + 2 * p + 1];
      unsigned u = pk_bf16(v0, v1);
      int colpair = ntp * 16 + p;
      int rowg = row0 + w * 16 + rowi;
      if (rowg < N_) {
        if (colpair < 64) xlb[(size_t)rowg * 64 + colpair] = u;
        else xrb[(size_t)rowg * 64 + colpair - 64] = u;
      }
    }
  }
}

// ---------------- CSR aggregation (r15 paired-pipeline body, bf16 buf out) --
__device__ __forceinline__ float ep8u(const uint4& u, const float* w) {
  float ep = up_lo(u.x) * w[0];
  ep = fmaf(up_hi(u.x), w[1], ep);
  ep = fmaf(up_lo(u.y), w[2], ep);
  ep = fmaf(up_hi(u.y), w[3], ep);
  ep = fmaf(up_lo(u.z), w[4], ep);
  ep = fmaf(up_hi(u.z), w[5], ep);
  ep = fmaf(up_lo(u.w), w[6], ep);
  ep = fmaf(up_hi(u.w), w[7], ep);
  return ep;
}

template <bool MASK>
__device__ __forceinline__ void pack4(int spre, int j, int cnt, int base, int l,
                                      const unsigned* __restrict__ xlb,
                                      const uint4* __restrict__ eas4,
                                      float xr0, float xr1,
                                      const float* w0, const float* w1,
                                      float2 attv,
                                      float& acc0, float& acc1, float& den) {
  int i0 = j;
  int i1 = j + 1, i2 = j + 2, i3 = j + 3;
  if (MASK) {
    i1 = (i1 < cnt) ? i1 : cnt - 1;
    i2 = (i2 < cnt) ? i2 : cnt - 1;
    i3 = (i3 < cnt) ? i3 : cnt - 1;
  }
  int s0 = __builtin_amdgcn_readlane(spre, i0);
  int s1 = __builtin_amdgcn_readlane(spre, i1);
  int s2 = __builtin_amdgcn_readlane(spre, i2);
  int s3 = __builtin_amdgcn_readlane(spre, i3);
  unsigned xu0 = xlb[(size_t)s0 * 64 + l];
  unsigned xu1 = xlb[(size_t)s1 * 64 + l];
  unsigned xu2 = xlb[(size_t)s2 * 64 + l];
  unsigned xu3 = xlb[(size_t)s3 * 64 + l];
  uint4 u0 = eas4[base + i0];
  uint4 u1 = eas4[base + i1];
  uint4 u2 = eas4[base + i2];
  uint4 u3 = eas4[base + i3];
  float x00 = up_lo(xu0), x01 = up_hi(xu0);
  float x10 = up_lo(xu1), x11 = up_hi(xu1);
  float x20 = up_lo(xu2), x21 = up_hi(xu2);
  float x30 = up_lo(xu3), x31 = up_hi(xu3);
  float m00 = x00 + xr0 + ep8u(u0, w0);
  float m01 = x01 + xr1 + ep8u(u0, w1);
  float m10 = x10 + xr0 + ep8u(u1, w0);
  float m11 = x11 + xr1 + ep8u(u1, w1);
  float m20 = x20 + xr0 + ep8u(u2, w0);
  float m21 = x21 + xr1 + ep8u(u2, w1);
  float m30 = x30 + xr0 + ep8u(u3, w0);
  float m31 = x31 + xr1 + ep8u(u3, w1);
  m00 = (m00 > 0.f) ? m00 : 0.2f * m00;
  m01 = (m01 > 0.f) ? m01 : 0.2f * m01;
  m10 = (m10 > 0.f) ? m10 : 0.2f * m10;
  m11 = (m11 > 0.f) ? m11 : 0.2f * m11;
  m20 = (m20 > 0.f) ? m20 : 0.2f * m20;
  m21 = (m21 > 0.f) ? m21 : 0.2f * m21;
  m30 = (m30 > 0.f) ? m30 : 0.2f * m30;
  m31 = (m31 > 0.f) ? m31 : 0.2f * m31;
  float p0 = fmaf(m00, attv.x, m01 * attv.y);
  float p1 = fmaf(m10, attv.x, m11 * attv.y);
  float p2 = fmaf(m20, attv.x, m21 * attv.y);
  float p3 = fmaf(m30, attv.x, m31 * attv.y);
  p0 = row_reduce16(p0);
  p1 = row_reduce16(p1);
  p2 = row_reduce16(p2);
  p3 = row_reduce16(p3);
  float e0v = __expf(p0), e1v = __expf(p1), e2v = __expf(p2), e3v = __expf(p3);
  if (MASK) {
    if (j + 1 >= cnt) e1v = 0.f;
    if (j + 2 >= cnt) e2v = 0.f;
    if (j + 3 >= cnt) e3v = 0.f;
  }
  acc0 = fmaf(e0v, x00, acc0); acc1 = fmaf(e0v, x01, acc1);
  acc0 = fmaf(e1v, x10, acc0); acc1 = fmaf(e1v, x11, acc1);
  acc0 = fmaf(e2v, x20, acc0); acc1 = fmaf(e2v, x21, acc1);
  acc0 = fmaf(e3v, x30, acc0); acc1 = fmaf(e3v, x31, acc1);
  den += (e0v + e1v) + (e2v + e3v);
}

__device__ __forceinline__ void solo_node(int e0, int e1, int l,
                                          const int* __restrict__ esrc,
                                          const unsigned* __restrict__ xlb,
                                          const uint4* __restrict__ eas4,
                                          float xr0, float xr1,
                                          const float* w0, const float* w1,
                                          float2 attv,
                                          float& acc0, float& acc1, float& den) {
  for (int base = e0; base < e1; base += 64) {
    int cnt = min(64, e1 - base);
    int spre = (base + l < e1) ? esrc[base + l] : 0;
    int j = 0;
    for (; j + 4 <= cnt; j += 4)
      pack4<false>(spre, j, cnt, base, l, xlb, eas4, xr0, xr1, w0, w1, attv, acc0, acc1, den);
    if (j < cnt)
      pack4<true>(spre, j, cnt, base, l, xlb, eas4, xr0, xr1, w0, w1, attv, acc0, acc1, den);
  }
}

__global__ __launch_bounds__(256) void agg_csr(const int* __restrict__ eoff,
                                               const int* __restrict__ esrc,
                                               const unsigned* __restrict__ easb,
                                               const float* __restrict__ Wel,
                                               const float* __restrict__ attl,
                                               const unsigned* __restrict__ xlb,
                                               const unsigned* __restrict__ xrb,
                                               const float* __restrict__ cb,
                                               unsigned short* __restrict__ bufs,
                                               float* __restrict__ ssum,
                                               float* __restrict__ ssq) {
  __shared__ float sA[256], sB[256], sC[256], sD[256];
  __shared__ uint4 eaLds[4][64];   // per-wave attr window (1 KB each)
  int t = threadIdx.x;
  int l = t & 63;
  int sub = t >> 6;
  int c0 = l * 2;
  uint4* eaW = &eaLds[sub][0];
  float w0[8], w1[8];
#pragma unroll
  for (int k = 0; k < 8; k++) {
    float2 wv = *(const float2*)&Wel[k * H_ + c0];
    w0[k] = wv.x; w1[k] = wv.y;
  }
  float2 attv = *(const float2*)&attl[c0];
  float2 cbv = *(const float2*)&cb[c0];
  const uint4* eas4 = (const uint4*)easb;
  float a1_0 = 0.f, a1_1 = 0.f, a2_0 = 0.f, a2_1 = 0.f;

  for (int pi = blockIdx.x * 4 + sub; pi < N_ / 2; pi += gridDim.x * 4) {
    int nA = 2 * pi, nB = nA + 1;
    int e0A = eoff[nA], e1A = eoff[nA + 1], e1B = eoff[nA + 2];
    unsigned xruA = xrb[(size_t)nA * 64 + l];
    unsigned xruB = xrb[(size_t)nB * 64 + l];
    int cE = e1B - e0A;
    float hA0, hA1, hB0, hB1;
    if (cE <= 64) {
      int cA = e1A - e0A, cB = e1B - e1A;
      // stage pair attrs to LDS (one coalesced load) + esrc chunk to lane reg
      if (l < cE) eaW[l] = eas4[e0A + l];
      int spre = (l < cE) ? esrc[e0A + l] : 0;
      __asm__ volatile("s_waitcnt lgkmcnt(0)" ::: "memory");
      int nPA = (cA + 3) >> 2;
      int nP = nPA + ((cB + 3) >> 2);
      float accA0 = 0.f, accA1 = 0.f, denA = 0.f;
      float accB0 = 0.f, accB1 = 0.f, denB = 0.f;
      unsigned xu0 = 0, xu1 = 0, xu2 = 0, xu3 = 0;
      int i0 = 0, i1 = 0, i2 = 0, i3 = 0;  // uniform pack indices (local)
      if (nP > 0) {  // prefetch pack 0
        bool isA = 0 < nPA;
        int off = isA ? 0 : cA;
        int cnt = isA ? cA : cB;
        int lim = off + cnt - 1;
        i0 = off;
        i1 = min(off + 1, lim); i2 = min(off + 2, lim); i3 = min(off + 3, lim);
        xu0 = xlb[(size_t)__builtin_amdgcn_readlane(spre, i0) * 64 + l];
        xu1 = xlb[(size_t)__builtin_amdgcn_readlane(spre, i1) * 64 + l];
        xu2 = xlb[(size_t)__builtin_amdgcn_readlane(spre, i2) * 64 + l];
        xu3 = xlb[(size_t)__builtin_amdgcn_readlane(spre, i3) * 64 + l];
      }
      for (int k = 0; k < nP; k++) {
        unsigned t0 = xu0, t1 = xu1, t2 = xu2, t3 = xu3;
        int ci0 = i0, ci1 = i1, ci2 = i2, ci3 = i3;
        bool isA = k < nPA;
        int j = isA ? 4 * k : 4 * (k - nPA);
        int cnt = isA ? cA : cB;
        if (k + 1 < nP) {  // prefetch pack k+1 (gathers only, 4 VGPR)
          bool pA = (k + 1) < nPA;
          int off2 = pA ? 0 : cA;
          int cnt2 = pA ? cA : cB;
          int j2 = pA ? 4 * (k + 1) : 4 * (k + 1 - nPA);
          int b2 = off2 + j2;
          int lim2 = off2 + cnt2 - 1;
          i0 = b2;
          i1 = min(b2 + 1, lim2); i2 = min(b2 + 2, lim2); i3 = min(b2 + 3, lim2);
          xu0 = xlb[(size_t)__builtin_amdgcn_readlane(spre, i0) * 64 + l];
          xu1 = xlb[(size_t)__builtin_amdgcn_readlane(spre, i1) * 64 + l];
          xu2 = xlb[(size_t)__builtin_amdgcn_readlane(spre, i2) * 64 + l];
          xu3 = xlb[(size_t)__builtin_amdgcn_readlane(spre, i3) * 64 + l];
        }
        // attrs from LDS (uniform broadcast reads)
        uint4 u0 = eaW[ci0], u1 = eaW[ci1], u2 = eaW[ci2], u3 = eaW[ci3];
        unsigned xrp = isA ? xruA : xruB;
        float xr0 = up_lo(xrp), xr1 = up_hi(xrp);
        float x00 = up_lo(t0), x01 = up_hi(t0);
        float x10 = up_lo(t1), x11 = up_hi(t1);
        float x20 = up_lo(t2), x21 = up_hi(t2);
        float x30 = up_lo(t3), x31 = up_hi(t3);
        float m00 = x00 + xr0 + ep8u(u0, w0);
        float m01 = x01 + xr1 + ep8u(u0, w1);
        float m10 = x10 + xr0 + ep8u(u1, w0);
        float m11 = x11 + xr1 + ep8u(u1, w1);
        float m20 = x20 + xr0 + ep8u(u2, w0);
        float m21 = x21 + xr1 + ep8u(u2, w1);
        float m30 = x30 + xr0 + ep8u(u3, w0);
        float m31 = x31 + xr1 + ep8u(u3, w1);
        m00 = (m00 > 0.f) ? m00 : 0.2f * m00;
        m01 = (m01 > 0.f) ? m01 : 0.2f * m01;
        m10 = (m10 > 0.f) ? m10 : 0.2f * m10;
        m11 = (m11 > 0.f) ? m11 : 0.2f * m11;
        m20 = (m20 > 0.f) ? m20 : 0.2f * m20;
        m21 = (m21 > 0.f) ? m21 : 0.2f * m21;
        m30 = (m30 > 0.f) ? m30 : 0.2f * m30;
        m31 = (m31 > 0.f) ? m31 : 0.2f * m31;
        float p0 = fmaf(m00, attv.x, m01 * attv.y);
        float p1 = fmaf(m10, attv.x, m11 * attv.y);
        float p2 = fmaf(m20, attv.x, m21 * attv.y);
        float p3 = fmaf(m30, attv.x, m31 * attv.y);
        p0 = row_reduce16(p0);
        p1 = row_reduce16(p1);
        p2 = row_reduce16(p2);
        p3 = row_reduce16(p3);
        float e0v = __expf(p0), e1v = __expf(p1), e2v = __expf(p2), e3v = __expf(p3);
        if (j + 1 >= cnt) e1v = 0.f;
        if (j + 2 >= cnt) e2v = 0.f;
        if (j + 3 >= cnt) e3v = 0.f;
        if (isA) {
          accA0 = fmaf(e0v, x00, accA0); accA1 = fmaf(e0v, x01, accA1);
          accA0 = fmaf(e1v, x10, accA0); accA1 = fmaf(e1v, x11, accA1);
          accA0 = fmaf(e2v, x20, accA0); accA1 = fmaf(e2v, x21, accA1);
          accA0 = fmaf(e3v, x30, accA0); accA1 = fmaf(e3v, x31, accA1);
          denA += (e0v + e1v) + (e2v + e3v);
        } else {
          accB0 = fmaf(e0v, x00, accB0); accB1 = fmaf(e0v, x01, accB1);
          accB0 = fmaf(e1v, x10, accB0); accB1 = fmaf(e1v, x11, accB1);
          accB0 = fmaf(e2v, x20, accB0); accB1 = fmaf(e2v, x21, accB1);
          accB0 = fmaf(e3v, x30, accB0); accB1 = fmaf(e3v, x31, accB1);
          denB += (e0v + e1v) + (e2v + e3v);
        }
      }
      float invA = 1.f / (denA + 1e-16f);
      float invB = 1.f / (denB + 1e-16f);
      hA0 = accA0 * invA + cbv.x; hA1 = accA1 * invA + cbv.y;
      hB0 = accB0 * invB + cbv.x; hB1 = accB1 * invB + cbv.y;
    } else {
      // rare fallback: pair window exceeds 64 edges -> solo path per node
      float accA0 = 0.f, accA1 = 0.f, denA = 0.f;
      float accB0 = 0.f, accB1 = 0.f, denB = 0.f;
      solo_node(e0A, e1A, l, esrc, xlb, eas4, up_lo(xruA), up_hi(xruA),
                w0, w1, attv, accA0, accA1, denA);
      solo_node(e1A, e1B, l, esrc, xlb, eas4, up_lo(xruB), up_hi(xruB),
                w0, w1, attv, accB0, accB1, denB);
      float invA = 1.f / (denA + 1e-16f);
      float invB = 1.f / (denB + 1e-16f);
      hA0 = accA0 * invA + cbv.x; hA1 = accA1 * invA + cbv.y;
      hB0 = accB0 * invB + cbv.x; hB1 = accB1 * invB + cbv.y;
    }
    // packed bf16 buf writes (one u32 per column pair)
    ((unsigned*)(bufs + (size_t)nA * H_))[l] = pk_bf16(hA0, hA1);
    ((unsigned*)(bufs + (size_t)nB * H_))[l] = pk_bf16(hB0, hB1);
    a1_0 += hA0 + hB0; a1_1 += hA1 + hB1;
    a2_0 = fmaf(hA0, hA0, a2_0); a2_0 = fmaf(hB0, hB0, a2_0);
    a2_1 = fmaf(hA1, hA1, a2_1); a2_1 = fmaf(hB1, hB1, a2_1);
  }
  sA[t] = a1_0; sB[t] = a1_1; sC[t] = a2_0; sD[t] = a2_1;
  __syncthreads();
  if (t < 64) {
    float r1 = sA[t] + sA[t + 64] + sA[t + 128] + sA[t + 192];
    float r2 = sB[t] + sB[t + 64] + sB[t + 128] + sB[t + 192];
    float r3 = sC[t] + sC[t + 64] + sC[t + 128] + sC[t + 192];
    float r4 = sD[t] + sD[t + 64] + sD[t + 128] + sD[t + 192];
    atomicAdd(&ssum[2 * t], r1);
    atomicAdd(&ssum[2 * t + 1], r2);
    atomicAdd(&ssq[2 * t], r3);
    atomicAdd(&ssq[2 * t + 1], r4);
  }
}

// ---------------- pooling with fused layer-2 residual (bf16 buf + bf16 xn) --
__global__ __launch_bounds__(128) void pool_residual(const int* __restrict__ goff,
                                                     const unsigned short* __restrict__ xnb,
                                                     const unsigned short* __restrict__ bufs,
                                                     const float* __restrict__ g,
                                                     const float* __restrict__ beta,
                                                     const float* __restrict__ ssum,
                                                     const float* __restrict__ ssq,
                                                     float rows_inv,
                                                     float* __restrict__ xg) {
  int gr = blockIdx.x;
  int t = threadIdx.x;
  int n0 = goff[gr], n1 = goff[gr + 1];
  float mm = ssum[t] * rows_inv;
  float rr = rsqrtf(ssq[t] * rows_inv - mm * mm + 1e-5f);
  float gg = g[t], bb = beta[t];
  float s = 0.f, mx = -INFINITY;
  for (int n = n0; n < n1; n++) {
    float hv = up_s(bufs[(size_t)n * H_ + t]);
    float w = gg * (hv - mm) * rr + bb;
    w = (w > 0.f) ? w : (__expf(w) - 1.f);
    float v = up_s(xnb[(size_t)n * H_ + t]) + w;
    s += v;
    mx = fmaxf(mx, v);
  }
  float c = (float)(n1 - n0);
  xg[gr * 384 + t] = s / fmaxf(c, 1.f);
  xg[gr * 384 + 128 + t] = (c > 0.f) ? mx : 0.f;
  xg[gr * 384 + 256 + t] = s;
}

// ---------------- t1 GEMM (raw output + colstats) ----------------
__global__ void mlp_gemm1(const float* __restrict__ A, const float* __restrict__ W,
                          const float* __restrict__ b, float* __restrict__ Y, int rows,
                          float* __restrict__ ssum, float* __restrict__ ssq) {
  __shared__ float xs[8][384];
  int t = threadIdx.x;  // 256
  int row0 = blockIdx.x * 8;
  for (int i = t; i < 8 * 384; i += 256) {
    int r = i / 384, k = i % 384;
    int row = row0 + r;
    xs[r][k] = (row < rows) ? A[row * 384 + k] : 0.f;
  }
  __syncthreads();
  float acc[8];
#pragma unroll
  for (int r = 0; r < 8; r++) acc[r] = 0.f;
  for (int k = 0; k < 384; k++) {
    float w = W[k * 256 + t];
#pragma unroll
    for (int r = 0; r < 8; r++) acc[r] = fmaf(xs[r][k], w, acc[r]);
  }
  float bb = b[t];
  float a1 = 0.f, a2 = 0.f;
#pragma unroll
  for (int r = 0; r < 8; r++) {
    int row = row0 + r;
    if (row < rows) {
      float v = acc[r] + bb;
      Y[row * 256 + t] = v;
      a1 += v;
      a2 = fmaf(v, v, a2);
    }
  }
  atomicAdd(&ssum[t], a1);
  atomicAdd(&ssq[t], a2);
}

// ---------------- t2 GEMM with inline BN+relu on input (u1 raw) -------------
__global__ void mlp_gemm2(const float* __restrict__ A,
                          const float* __restrict__ g4, const float* __restrict__ be4,
                          const float* __restrict__ s4, const float* __restrict__ q4,
                          float rinv,
                          const float* __restrict__ W, const float* __restrict__ b,
                          float* __restrict__ Y, int rows,
                          float* __restrict__ ssum, float* __restrict__ ssq) {
  __shared__ float xs[8][256];
  int t = threadIdx.x;  // 128
  int row0 = blockIdx.x * 8;
  for (int i = t; i < 8 * 256; i += 128) {
    int r = i >> 8, k = i & 255;
    int row = row0 + r;
    float v = 0.f;
    if (row < rows) {
      float m = s4[k] * rinv;
      float rs = rsqrtf(q4[k] * rinv - m * m + 1e-5f);
      v = fmaxf(g4[k] * (A[row * 256 + k] - m) * rs + be4[k], 0.f);
    }
    xs[r][k] = v;
  }
  __syncthreads();
  float acc[8];
#pragma unroll
  for (int r = 0; r < 8; r++) acc[r] = 0.f;
  for (int k = 0; k < 256; k++) {
    float w = W[k * 128 + t];
#pragma unroll
    for (int r = 0; r < 8; r++) acc[r] = fmaf(xs[r][k], w, acc[r]);
  }
  float bb = b[t];
  float a1 = 0.f, a2 = 0.f;
#pragma unroll
  for (int r = 0; r < 8; r++) {
    int row = row0 + r;
    if (row < rows) {
      float v = acc[r] + bb;
      Y[row * 128 + t] = v;
      a1 += v;
      a2 = fmaf(v, v, a2);
    }
  }
  atomicAdd(&ssum[t], a1);
  atomicAdd(&ssq[t], a2);
}

// ---------------- head with inline BN+relu on input (u2 raw) ----------------
__global__ __launch_bounds__(64) void head_kernel(const float* __restrict__ u,
                                                  const float* __restrict__ g5,
                                                  const float* __restrict__ be5,
                                                  const float* __restrict__ s5,
                                                  const float* __restrict__ q5,
                                                  float rinv,
                                                  const float* __restrict__ W,
                                                  const float* __restrict__ b,
                                                  float* __restrict__ out) {
  __shared__ float row[128];
  int gblk = blockIdx.x;
  int t = threadIdx.x;
#pragma unroll
  for (int h = 0; h < 2; h++) {
    int c = t + h * 64;
    float m = s5[c] * rinv;
    float rs = rsqrtf(q5[c] * rinv - m * m + 1e-5f);
    float v = g5[c] * (u[gblk * 128 + c] - m) * rs + be5[c];
    row[c] = fmaxf(v, 0.f);
  }
  __syncthreads();
  if (t < 12) {
    float acc = b[t];
    for (int k = 0; k < 128; k++) acc = fmaf(row[k], W[k * 12 + t], acc);
    out[gblk * 12 + t] = 1.f / (1.f + expf(-acc));
  }
}

// ---------------- launcher ----------------
extern "C" void kernel_launch(void* const* d_in, const int* in_sizes, int n_in, void* d_out,
                              int out_size, void* d_ws, size_t ws_size, hipStream_t stream) {
  (void)in_sizes; (void)n_in; (void)out_size; (void)ws_size;
  const float* x       = (const float*)d_in[0];
  const int*   ei      = (const int*)d_in[1];
  const float* ea      = (const float*)d_in[2];
  const int*   batch   = (const int*)d_in[3];
  const float* in_W    = (const float*)d_in[4];
  const float* in_b    = (const float*)d_in[5];
  const float* in_g    = (const float*)d_in[6];
  const float* in_beta = (const float*)d_in[7];
  const float* Wl      = (const float*)d_in[8];
  const float* Wr      = (const float*)d_in[9];
  const float* We      = (const float*)d_in[10];
  const float* att     = (const float*)d_in[11];
  const float* conv_b  = (const float*)d_in[12];
  const float* bn_g    = (const float*)d_in[13];
  const float* bn_b    = (const float*)d_in[14];
  const float* t1_W    = (const float*)d_in[15];
  const float* t1_b    = (const float*)d_in[16];
  const float* t1_g    = (const float*)d_in[17];
  const float* t1_beta = (const float*)d_in[18];
  const float* t2_W    = (const float*)d_in[19];
  const float* t2_b    = (const float*)d_in[20];
  const float* t2_g    = (const float*)d_in[21];
  const float* t2_beta = (const float*)d_in[22];
  const float* head_W  = (const float*)d_in[23];
  const float* head_b  = (const float*)d_in[24];
  float* out = (float*)d_out;

  float* p = (float*)d_ws;
  float* xn    = p; p += N_ * H_;   // used as bf16 (half occupied)
  float* buf   = p; p += N_ * H_;   // used as bf16 (half occupied)
  float* xg    = p; p += G_ * 384;
  float* u1    = p; p += G_ * 256;
  float* u2    = p; p += G_ * 128;
  float* sstat = p; p += 6 * 512;   // zeroed region starts here
  int* ip = (int*)p;
  int* deg    = ip; ip += N_;       // contiguous with sstat (one memset)
  int* pref   = ip; ip += 64;       // scan publish flags (zero-init sentinel)
  int* eoff   = ip; ip += N_ + 1;
  int* cursor = ip; ip += N_;
  int* goff   = ip; ip += G_ + 1;
  int* esrc   = ip; ip += E_;
  unsigned* up = (unsigned*)ip;
  unsigned* xlb  = up; up += (size_t)N_ * 64;
  unsigned* xrb  = up; up += (size_t)N_ * 64;
  unsigned* easb = up; up += (size_t)E_ * 4;
  unsigned short* wpack = (unsigned short*)up; up += 3 * 32768 / 2;
  unsigned short* bufs = (unsigned short*)buf;
  unsigned short* xnb = (unsigned short*)xn;

#define SSUM(s) (sstat + (s) * 512)
#define SSQ(s)  (sstat + (s) * 512 + 256)

  // single zeroing memset: sstat (12 KB) | deg (200 KB) | pref (256 B)
  hipMemsetAsync(sstat, 0, (size_t)(6 * 512 + N_ + 64) * sizeof(int), stream);

  // prep: hist + goff + pack_weights + in_gemm (stats -> stage 0)
  prep_kernel<<<HIST_B + GOFF_B + PACK_B + INGEMM_B, 256, 0, stream>>>(
      ei, batch, Wl, Wr, x, in_W, in_b, deg, goff, wpack, bufs, SSUM(0), SSQ(0));

  // CSR: single-pass scan + scatter
  scan_onepass<<<49, 1024, 0, stream>>>(deg, eoff, cursor, pref, N_);
  edge_scatter<<<(E_ + 255) / 256, 256, 0, stream>>>(ei, ea, cursor, esrc, easb);

  // ---- 3 GATv2 layers (conv stats of layer l -> stage l+1) ----
  const float rnInv = 1.f / N_;
  for (int l = 0; l < 3; l++) {
    if (l == 0) {
      gemm_mfma<1><<<782, 256, 0, stream>>>(xnb, bufs, in_g, in_beta, SSUM(0), SSQ(0), rnInv,
                                            wpack + (size_t)l * 32768, xlb, xrb);
    } else {
      gemm_mfma<2><<<782, 256, 0, stream>>>(xnb, bufs, bn_g + (l - 1) * H_, bn_b + (l - 1) * H_,
                                            SSUM(l), SSQ(l), rnInv,
                                            wpack + (size_t)l * 32768, xlb, xrb);
    }
    agg_csr<<<2048, 256, 0, stream>>>(eoff, esrc, easb, We + l * 8 * H_, att + l * H_,
                                      xlb, xrb, conv_b + l * H_, bufs, SSUM(l + 1), SSQ(l + 1));
  }

  // ---- pooling with fused layer-2 residual (stage 3 stats) ----
  pool_residual<<<G_, 128, 0, stream>>>(goff, xnb, bufs, bn_g + 2 * H_, bn_b + 2 * H_,
                                        SSUM(3), SSQ(3), rnInv, xg);

  // ---- t1 (raw + stats 4), t2 (inline BN of u1, raw + stats 5), head ----
  const float rgInv = 1.f / G_;
  mlp_gemm1<<<G_ / 8, 256, 0, stream>>>(xg, t1_W, t1_b, u1, G_, SSUM(4), SSQ(4));
  mlp_gemm2<<<G_ / 8, 128, 0, stream>>>(u1, t1_g, t1_beta, SSUM(4), SSQ(4), rgInv,
                                        t2_W, t2_b, u2, G_, SSUM(5), SSQ(5));
  head_kernel<<<G_, 64, 0, stream>>>(u2, t2_g, t2_beta, SSUM(5), SSQ(5), rgInv,
                                     head_W, head_b, out);
#undef SSUM
#undef SSQ
}

// Round 13
// 777.501 us; speedup vs baseline: 1.0955x; 1.0955x over previous
//
#include <hip/hip_runtime.h>
#include <math.h>

// ToxicityGATv2 — round 22: REVERT to round-20 exactly (779.6us best).
// r21's ping-pong B staging cut gemm residency 4 -> 3 blocks/CU (LDS 37888 ->
// 54272 B) and regressed 72us — third instance of the occupancy trap (r10,
// r16, r21): ILP bought with residency loses on this kernel set.
// State: bf16 buf + bf16 xn (traffic floor), drainless gemm epilogue,
// merged prep, one-pass scan, paired-pipeline agg (cross-XCD gather floor).

constexpr int N_ = 50000;
constexpr int E_ = 400000;
constexpr int G_ = 2000;
constexpr int H_ = 128;
constexpr int IN_ = 39;

constexpr int HIST_B = 1024;
constexpr int GOFF_B = (N_ + 255) / 256;      // 196
constexpr int PACK_B = 384;
constexpr int INGEMM_B = (N_ + 31) / 32;      // 1563

typedef __attribute__((ext_vector_type(8))) short bf16x8;
typedef __attribute__((ext_vector_type(4))) float f32x4;

// ---------------- bf16 pack/unpack (RNE) ----------------
__device__ __forceinline__ unsigned pk_bf16(float a, float b) {
  unsigned ua = __float_as_uint(a);
  unsigned ub = __float_as_uint(b);
  ua = (ua + 0x7fffu + ((ua >> 16) & 1u)) >> 16;
  ub = (ub + 0x7fffu + ((ub >> 16) & 1u)) & 0xffff0000u;
  return ua | ub;
}
__device__ __forceinline__ unsigned short bf16_1(float x) {
  unsigned u = __float_as_uint(x);
  u = (u + 0x7fffu + ((u >> 16) & 1u)) >> 16;
  return (unsigned short)u;
}
__device__ __forceinline__ float up_lo(unsigned u) { return __uint_as_float(u << 16); }
__device__ __forceinline__ float up_hi(unsigned u) { return __uint_as_float(u & 0xffff0000u); }
__device__ __forceinline__ float up_s(unsigned short s) {
  return __uint_as_float(((unsigned)s) << 16);
}

// ---------------- DPP rotate-reduce over 16-lane rows (VALU pipe, no LDS) ----
template <int CTRL>
__device__ __forceinline__ float dpp_radd(float x) {
  int y = __builtin_amdgcn_update_dpp(0, __float_as_int(x), CTRL, 0xF, 0xF, false);
  return x + __int_as_float(y);
}
__device__ __forceinline__ float row_reduce16(float p) {
  p = dpp_radd<0x121>(p);  // row_ror:1
  p = dpp_radd<0x122>(p);  // row_ror:2
  p = dpp_radd<0x124>(p);  // row_ror:4
  p = dpp_radd<0x128>(p);  // row_ror:8
  return p;
}

// ---------------- merged prep: hist | goff | pack_weights | in_gemm ----------
__global__ __launch_bounds__(256) void prep_kernel(const int* __restrict__ ei,
                                                   const int* __restrict__ batch,
                                                   const float* __restrict__ Wl,
                                                   const float* __restrict__ Wr,
                                                   const float* __restrict__ x,
                                                   const float* __restrict__ in_W,
                                                   const float* __restrict__ in_b,
                                                   int* __restrict__ deg,
                                                   int* __restrict__ goff,
                                                   unsigned short* __restrict__ wpack,
                                                   unsigned short* __restrict__ yb,
                                                   float* __restrict__ ssum,
                                                   float* __restrict__ ssq) {
  int b = blockIdx.x;
  int t = threadIdx.x;
  if (b < HIST_B) {
    for (int i = b * 256 + t; i < E_; i += HIST_B * 256)
      atomicAdd(&deg[ei[E_ + i]], 1);
    return;
  }
  b -= HIST_B;
  if (b < GOFF_B) {
    int i = b * 256 + t;
    if (i >= N_) return;
    int bi = batch[i];
    int bp = (i == 0) ? -1 : batch[i - 1];
    for (int g = bp + 1; g <= bi; g++) goff[g] = i;
    if (i == N_ - 1) {
      for (int g = bi + 1; g <= G_; g++) goff[g] = N_;
    }
    return;
  }
  b -= GOFF_B;
  if (b < PACK_B) {
    int i = b * 256 + t;
    if (i >= 3 * 128 * 256) return;
    int l = i >> 15;
    int rem = i & 32767;
    int k = rem >> 8;
    int n = rem & 255;
    const float* Wsrc = (n < 128) ? (Wl + l * H_ * H_) : (Wr + l * H_ * H_);
    int nn = n & 127;
    wpack[(size_t)l * 32768 + n * 128 + k] = bf16_1(Wsrc[k * H_ + nn]);
    return;
  }
  b -= PACK_B;
  // ---- in_gemm body (bf16 output) ----
  __shared__ float xs[32][40];
  __shared__ float s1[256], s2[256];
  int row0 = b * 32;
  for (int i = t; i < 32 * IN_; i += 256) {
    int r = i / IN_, k = i % IN_;
    int row = row0 + r;
    xs[r][k] = (row < N_) ? x[row * IN_ + k] : 0.f;
  }
  __syncthreads();
  int col = t & 127;
  int half = t >> 7;
  float acc[16];
#pragma unroll
  for (int r = 0; r < 16; r++) acc[r] = 0.f;
  for (int k = 0; k < IN_; k++) {
    float w = in_W[k * H_ + col];
#pragma unroll
    for (int r = 0; r < 16; r++) acc[r] = fmaf(xs[half * 16 + r][k], w, acc[r]);
  }
  float bb = in_b[col];
  float a1 = 0.f, a2 = 0.f;
#pragma unroll
  for (int r = 0; r < 16; r++) {
    int row = row0 + half * 16 + r;
    float v = acc[r] + bb;
    if (row < N_) {
      yb[(size_t)row * H_ + col] = bf16_1(v);
      a1 += v;
      a2 = fmaf(v, v, a2);
    }
  }
  s1[t] = a1; s2[t] = a2;
  __syncthreads();
  if (t < 128) {
    atomicAdd(&ssum[t], s1[t] + s1[t + 128]);
    atomicAdd(&ssq[t], s2[t] + s2[t + 128]);
  }
}

// ---------------- single-pass chained scan (49 co-resident blocks) ----------
__global__ __launch_bounds__(1024) void scan_onepass(const int* __restrict__ deg,
                                                     int* __restrict__ eoff,
                                                     int* __restrict__ cursor,
                                                     int* __restrict__ pref, int n) {
  __shared__ int wsum[16];
  __shared__ int sbase;
  int t = threadIdx.x, lane = t & 63, wid = t >> 6;
  int b = blockIdx.x;
  int idx = b * 1024 + t;
  int v = (idx < n) ? deg[idx] : 0;
  int x = v;
#pragma unroll
  for (int off = 1; off < 64; off <<= 1) {
    int y = __shfl_up(x, off, 64);
    if (lane >= off) x += y;
  }
  if (lane == 63) wsum[wid] = x;
  __syncthreads();
  if (t == 0) {
    int acc = 0;
#pragma unroll
    for (int w = 0; w < 16; w++) { int tmp = wsum[w]; wsum[w] = acc; acc += tmp; }
    int prev = 0;
    if (b > 0) {
      int got;
      do { got = atomicAdd(&pref[b - 1], 0); } while (got == 0);  // +1 sentinel
      prev = got - 1;
    }
    atomicExch(&pref[b], prev + acc + 1);
    sbase = prev;
  }
  __syncthreads();
  if (idx < n) {
    int e = sbase + wsum[wid] + x - v;
    eoff[idx] = e;
    cursor[idx] = e;
    if (idx == n - 1) eoff[n] = E_;
  }
}

// ---------------- edge scatter (bf16 attrs) ----------------
__global__ __launch_bounds__(256) void edge_scatter(const int* __restrict__ ei,
                                                    const float* __restrict__ ea,
                                                    int* __restrict__ cursor,
                                                    int* __restrict__ esrc,
                                                    unsigned* __restrict__ easb) {
  int e = blockIdx.x * 256 + threadIdx.x;
  if (e >= E_) return;
  int src = ei[e];
  int dst = ei[E_ + e];
  int j = atomicAdd(&cursor[dst], 1);
  esrc[j] = src;
  const float4* eav = (const float4*)(ea + (size_t)e * 8);
  float4 a0 = eav[0], a1 = eav[1];
  uint4 o;
  o.x = pk_bf16(a0.x, a0.y);
  o.y = pk_bf16(a0.z, a0.w);
  o.z = pk_bf16(a1.x, a1.y);
  o.w = pk_bf16(a1.z, a1.w);
  ((uint4*)easb)[j] = o;
}

// ---------------- MFMA node GEMM (pre-packed bf16 B, bf16 buf + bf16 xn) ----
// MODE 1: v=relu(bn(buf)); xn=v.  MODE 2: v=xn+elu(bn(buf)); xn=v.
template <int MODE>
__global__ __launch_bounds__(256) void gemm_mfma(unsigned short* __restrict__ xnb,
                                                 const unsigned short* __restrict__ bufs,
                                                 const float* __restrict__ g,
                                                 const float* __restrict__ beta,
                                                 const float* __restrict__ ssum,
                                                 const float* __restrict__ ssq,
                                                 float rows_inv,
                                                 const unsigned short* __restrict__ wp,
                                                 unsigned* __restrict__ xlb,
                                                 unsigned* __restrict__ xrb) {
  __shared__ char smem[17408 + 20480];
  short (*a_s)[136] = (short(*)[136])smem;              // 64 rows x 128 k (pad 136)
  short (*b_s)[40] = (short(*)[40])(smem + 17408);      // 256 n x 32 k (pad 40)
  float* t2base = (float*)(smem + 17408);               // epilogue reuse
  int t = threadIdx.x;
  int lane = t & 63, w = t >> 6;
  int quad = lane >> 4, lc = lane & 15;
  int row0 = blockIdx.x * 64;

  // ---- stage A (fused BN epilogue, bf16 xn updated, bf16 into LDS) ----
  {
    int r = t >> 2;
    int row = row0 + r;
    int kb0 = (t & 3) * 32;
    bool valid = row < N_;
    for (int kk = 0; kk < 32; kk += 4) {
      int c = kb0 + kk;
      float4 v = make_float4(0.f, 0.f, 0.f, 0.f);
      uint2 pk;
      if (valid) {
        uint2 bp = *(const uint2*)&bufs[(size_t)row * H_ + c];
        float bx = up_lo(bp.x), by = up_hi(bp.x), bz = up_lo(bp.y), bw = up_hi(bp.y);
        float4 gv = *(const float4*)&g[c];
        float4 be = *(const float4*)&beta[c];
        float4 s1 = *(const float4*)&ssum[c];
        float4 s2 = *(const float4*)&ssq[c];
        float m0 = s1.x * rows_inv, m1 = s1.y * rows_inv, m2 = s1.z * rows_inv, m3 = s1.w * rows_inv;
        float r0 = rsqrtf(s2.x * rows_inv - m0 * m0 + 1e-5f);
        float r1 = rsqrtf(s2.y * rows_inv - m1 * m1 + 1e-5f);
        float r2 = rsqrtf(s2.z * rows_inv - m2 * m2 + 1e-5f);
        float r3 = rsqrtf(s2.w * rows_inv - m3 * m3 + 1e-5f);
        float t0 = gv.x * (bx - m0) * r0 + be.x;
        float t1 = gv.y * (by - m1) * r1 + be.y;
        float t2 = gv.z * (bz - m2) * r2 + be.z;
        float t3 = gv.w * (bw - m3) * r3 + be.w;
        if (MODE == 1) {
          v = make_float4(fmaxf(t0, 0.f), fmaxf(t1, 0.f), fmaxf(t2, 0.f), fmaxf(t3, 0.f));
        } else {
          uint2 xo = *(const uint2*)&xnb[(size_t)row * H_ + c];
          float x0 = up_lo(xo.x), x1 = up_hi(xo.x), x2 = up_lo(xo.y), x3 = up_hi(xo.y);
          v.x = x0 + ((t0 > 0.f) ? t0 : (__expf(t0) - 1.f));
          v.y = x1 + ((t1 > 0.f) ? t1 : (__expf(t1) - 1.f));
          v.z = x2 + ((t2 > 0.f) ? t2 : (__expf(t2) - 1.f));
          v.w = x3 + ((t3 > 0.f) ? t3 : (__expf(t3) - 1.f));
        }
        pk.x = pk_bf16(v.x, v.y);
        pk.y = pk_bf16(v.z, v.w);
        *(uint2*)&xnb[(size_t)row * H_ + c] = pk;
      } else {
        pk.x = 0; pk.y = 0;
      }
      *(uint2*)&a_s[r][c] = pk;
    }
  }

  f32x4 acc[16];
#pragma unroll
  for (int nt = 0; nt < 16; nt++) acc[nt] = (f32x4){0.f, 0.f, 0.f, 0.f};

  for (int kb = 0; kb < 4; kb++) {
    __syncthreads();
    // stage B chunk: vectorized copy from pre-packed weights (16 KB)
    for (int i = t; i < 1024; i += 256) {
      int n = i >> 2;
      int k8 = (i & 3) * 8;
      *(uint4*)&b_s[n][k8] = *(const uint4*)&wp[(size_t)n * 128 + kb * 32 + k8];
    }
    __syncthreads();
    bf16x8 av = *(const bf16x8*)&a_s[w * 16 + lc][kb * 32 + quad * 8];
#pragma unroll
    for (int nt = 0; nt < 16; nt++) {
      bf16x8 bv = *(const bf16x8*)&b_s[nt * 16 + lc][quad * 8];
      acc[nt] = __builtin_amdgcn_mfma_f32_16x16x32_bf16(av, bv, acc[nt], 0, 0, 0);
    }
  }
  __syncthreads();  // b_s -> t2 reuse

  // ---- epilogue: transpose 16x32 chunks via LDS, packed coalesced stores ----
  // (drainless per r20: t2 is wave-private, DS ops in-order per wave,
  //  compiler inserts precise waitcnts for RAW deps)
  float* t2 = t2base + w * 544;  // 16 rows x 34 cols fp32, per-wave private
  for (int ntp = 0; ntp < 8; ntp++) {
#pragma unroll
    for (int rr = 0; rr < 4; rr++) {
      t2[(quad * 4 + rr) * 34 + lc] = acc[2 * ntp][rr];
      t2[(quad * 4 + rr) * 34 + 16 + lc] = acc[2 * ntp + 1][rr];
    }
#pragma unroll
    for (int it = 0; it < 4; it++) {
      int item = lane + it * 64;
      int p = item & 15, rowi = item >> 4;
      float v0 = t2[rowi * 34 + 2 * p];
      float v1 = t2[rowi * 34 + 2 * p + 1];
      unsigned u = pk_bf16(v0, v1);
      int colpair = ntp * 16 + p;
      int rowg = row0 + w * 16 + rowi;
      if (rowg < N_) {
        if (colpair < 64) xlb[(size_t)rowg * 64 + colpair] = u;
        else xrb[(size_t)rowg * 64 + colpair - 64] = u;
      }
    }
  }
}

// ---------------- CSR aggregation (r15 paired-pipeline body, bf16 buf out) --
__device__ __forceinline__ float ep8u(const uint4& u, const float* w) {
  float ep = up_lo(u.x) * w[0];
  ep = fmaf(up_hi(u.x), w[1], ep);
  ep = fmaf(up_lo(u.y), w[2], ep);
  ep = fmaf(up_hi(u.y), w[3], ep);
  ep = fmaf(up_lo(u.z), w[4], ep);
  ep = fmaf(up_hi(u.z), w[5], ep);
  ep = fmaf(up_lo(u.w), w[6], ep);
  ep = fmaf(up_hi(u.w), w[7], ep);
  return ep;
}

template <bool MASK>
__device__ __forceinline__ void pack4(int spre, int j, int cnt, int base, int l,
                                      const unsigned* __restrict__ xlb,
                                      const uint4* __restrict__ eas4,
                                      float xr0, float xr1,
                                      const float* w0, const float* w1,
                                      float2 attv,
                                      float& acc0, float& acc1, float& den) {
  int i0 = j;
  int i1 = j + 1, i2 = j + 2, i3 = j + 3;
  if (MASK) {
    i1 = (i1 < cnt) ? i1 : cnt - 1;
    i2 = (i2 < cnt) ? i2 : cnt - 1;
    i3 = (i3 < cnt) ? i3 : cnt - 1;
  }
  int s0 = __builtin_amdgcn_readlane(spre, i0);
  int s1 = __builtin_amdgcn_readlane(spre, i1);
  int s2 = __builtin_amdgcn_readlane(spre, i2);
  int s3 = __builtin_amdgcn_readlane(spre, i3);
  unsigned xu0 = xlb[(size_t)s0 * 64 + l];
  unsigned xu1 = xlb[(size_t)s1 * 64 + l];
  unsigned xu2 = xlb[(size_t)s2 * 64 + l];
  unsigned xu3 = xlb[(size_t)s3 * 64 + l];
  uint4 u0 = eas4[base + i0];
  uint4 u1 = eas4[base + i1];
  uint4 u2 = eas4[base + i2];
  uint4 u3 = eas4[base + i3];
  float x00 = up_lo(xu0), x01 = up_hi(xu0);
  float x10 = up_lo(xu1), x11 = up_hi(xu1);
  float x20 = up_lo(xu2), x21 = up_hi(xu2);
  float x30 = up_lo(xu3), x31 = up_hi(xu3);
  float m00 = x00 + xr0 + ep8u(u0, w0);
  float m01 = x01 + xr1 + ep8u(u0, w1);
  float m10 = x10 + xr0 + ep8u(u1, w0);
  float m11 = x11 + xr1 + ep8u(u1, w1);
  float m20 = x20 + xr0 + ep8u(u2, w0);
  float m21 = x21 + xr1 + ep8u(u2, w1);
  float m30 = x30 + xr0 + ep8u(u3, w0);
  float m31 = x31 + xr1 + ep8u(u3, w1);
  m00 = (m00 > 0.f) ? m00 : 0.2f * m00;
  m01 = (m01 > 0.f) ? m01 : 0.2f * m01;
  m10 = (m10 > 0.f) ? m10 : 0.2f * m10;
  m11 = (m11 > 0.f) ? m11 : 0.2f * m11;
  m20 = (m20 > 0.f) ? m20 : 0.2f * m20;
  m21 = (m21 > 0.f) ? m21 : 0.2f * m21;
  m30 = (m30 > 0.f) ? m30 : 0.2f * m30;
  m31 = (m31 > 0.f) ? m31 : 0.2f * m31;
  float p0 = fmaf(m00, attv.x, m01 * attv.y);
  float p1 = fmaf(m10, attv.x, m11 * attv.y);
  float p2 = fmaf(m20, attv.x, m21 * attv.y);
  float p3 = fmaf(m30, attv.x, m31 * attv.y);
  p0 = row_reduce16(p0);
  p1 = row_reduce16(p1);
  p2 = row_reduce16(p2);
  p3 = row_reduce16(p3);
  float e0v = __expf(p0), e1v = __expf(p1), e2v = __expf(p2), e3v = __expf(p3);
  if (MASK) {
    if (j + 1 >= cnt) e1v = 0.f;
    if (j + 2 >= cnt) e2v = 0.f;
    if (j + 3 >= cnt) e3v = 0.f;
  }
  acc0 = fmaf(e0v, x00, acc0); acc1 = fmaf(e0v, x01, acc1);
  acc0 = fmaf(e1v, x10, acc0); acc1 = fmaf(e1v, x11, acc1);
  acc0 = fmaf(e2v, x20, acc0); acc1 = fmaf(e2v, x21, acc1);
  acc0 = fmaf(e3v, x30, acc0); acc1 = fmaf(e3v, x31, acc1);
  den += (e0v + e1v) + (e2v + e3v);
}

__device__ __forceinline__ void solo_node(int e0, int e1, int l,
                                          const int* __restrict__ esrc,
                                          const unsigned* __restrict__ xlb,
                                          const uint4* __restrict__ eas4,
                                          float xr0, float xr1,
                                          const float* w0, const float* w1,
                                          float2 attv,
                                          float& acc0, float& acc1, float& den) {
  for (int base = e0; base < e1; base += 64) {
    int cnt = min(64, e1 - base);
    int spre = (base + l < e1) ? esrc[base + l] : 0;
    int j = 0;
    for (; j + 4 <= cnt; j += 4)
      pack4<false>(spre, j, cnt, base, l, xlb, eas4, xr0, xr1, w0, w1, attv, acc0, acc1, den);
    if (j < cnt)
      pack4<true>(spre, j, cnt, base, l, xlb, eas4, xr0, xr1, w0, w1, attv, acc0, acc1, den);
  }
}

__global__ __launch_bounds__(256) void agg_csr(const int* __restrict__ eoff,
                                               const int* __restrict__ esrc,
                                               const unsigned* __restrict__ easb,
                                               const float* __restrict__ Wel,
                                               const float* __restrict__ attl,
                                               const unsigned* __restrict__ xlb,
                                               const unsigned* __restrict__ xrb,
                                               const float* __restrict__ cb,
                                               unsigned short* __restrict__ bufs,
                                               float* __restrict__ ssum,
                                               float* __restrict__ ssq) {
  __shared__ float sA[256], sB[256], sC[256], sD[256];
  __shared__ uint4 eaLds[4][64];   // per-wave attr window (1 KB each)
  int t = threadIdx.x;
  int l = t & 63;
  int sub = t >> 6;
  int c0 = l * 2;
  uint4* eaW = &eaLds[sub][0];
  float w0[8], w1[8];
#pragma unroll
  for (int k = 0; k < 8; k++) {
    float2 wv = *(const float2*)&Wel[k * H_ + c0];
    w0[k] = wv.x; w1[k] = wv.y;
  }
  float2 attv = *(const float2*)&attl[c0];
  float2 cbv = *(const float2*)&cb[c0];
  const uint4* eas4 = (const uint4*)easb;
  float a1_0 = 0.f, a1_1 = 0.f, a2_0 = 0.f, a2_1 = 0.f;

  for (int pi = blockIdx.x * 4 + sub; pi < N_ / 2; pi += gridDim.x * 4) {
    int nA = 2 * pi, nB = nA + 1;
    int e0A = eoff[nA], e1A = eoff[nA + 1], e1B = eoff[nA + 2];
    unsigned xruA = xrb[(size_t)nA * 64 + l];
    unsigned xruB = xrb[(size_t)nB * 64 + l];
    int cE = e1B - e0A;
    float hA0, hA1, hB0, hB1;
    if (cE <= 64) {
      int cA = e1A - e0A, cB = e1B - e1A;
      // stage pair attrs to LDS (one coalesced load) + esrc chunk to lane reg
      if (l < cE) eaW[l] = eas4[e0A + l];
      int spre = (l < cE) ? esrc[e0A + l] : 0;
      __asm__ volatile("s_waitcnt lgkmcnt(0)" ::: "memory");
      int nPA = (cA + 3) >> 2;
      int nP = nPA + ((cB + 3) >> 2);
      float accA0 = 0.f, accA1 = 0.f, denA = 0.f;
      float accB0 = 0.f, accB1 = 0.f, denB = 0.f;
      unsigned xu0 = 0, xu1 = 0, xu2 = 0, xu3 = 0;
      int i0 = 0, i1 = 0, i2 = 0, i3 = 0;  // uniform pack indices (local)
      if (nP > 0) {  // prefetch pack 0
        bool isA = 0 < nPA;
        int off = isA ? 0 : cA;
        int cnt = isA ? cA : cB;
        int lim = off + cnt - 1;
        i0 = off;
        i1 = min(off + 1, lim); i2 = min(off + 2, lim); i3 = min(off + 3, lim);
        xu0 = xlb[(size_t)__builtin_amdgcn_readlane(spre, i0) * 64 + l];
        xu1 = xlb[(size_t)__builtin_amdgcn_readlane(spre, i1) * 64 + l];
        xu2 = xlb[(size_t)__builtin_amdgcn_readlane(spre, i2) * 64 + l];
        xu3 = xlb[(size_t)__builtin_amdgcn_readlane(spre, i3) * 64 + l];
      }
      for (int k = 0; k < nP; k++) {
        unsigned t0 = xu0, t1 = xu1, t2 = xu2, t3 = xu3;
        int ci0 = i0, ci1 = i1, ci2 = i2, ci3 = i3;
        bool isA = k < nPA;
        int j = isA ? 4 * k : 4 * (k - nPA);
        int cnt = isA ? cA : cB;
        if (k + 1 < nP) {  // prefetch pack k+1 (gathers only, 4 VGPR)
          bool pA = (k + 1) < nPA;
          int off2 = pA ? 0 : cA;
          int cnt2 = pA ? cA : cB;
          int j2 = pA ? 4 * (k + 1) : 4 * (k + 1 - nPA);
          int b2 = off2 + j2;
          int lim2 = off2 + cnt2 - 1;
          i0 = b2;
          i1 = min(b2 + 1, lim2); i2 = min(b2 + 2, lim2); i3 = min(b2 + 3, lim2);
          xu0 = xlb[(size_t)__builtin_amdgcn_readlane(spre, i0) * 64 + l];
          xu1 = xlb[(size_t)__builtin_amdgcn_readlane(spre, i1) * 64 + l];
          xu2 = xlb[(size_t)__builtin_amdgcn_readlane(spre, i2) * 64 + l];
          xu3 = xlb[(size_t)__builtin_amdgcn_readlane(spre, i3) * 64 + l];
        }
        // attrs from LDS (uniform broadcast reads)
        uint4 u0 = eaW[ci0], u1 = eaW[ci1], u2 = eaW[ci2], u3 = eaW[ci3];
        unsigned xrp = isA ? xruA : xruB;
        float xr0 = up_lo(xrp), xr1 = up_hi(xrp);
        float x00 = up_lo(t0), x01 = up_hi(t0);
        float x10 = up_lo(t1), x11 = up_hi(t1);
        float x20 = up_lo(t2), x21 = up_hi(t2);
        float x30 = up_lo(t3), x31 = up_hi(t3);
        float m00 = x00 + xr0 + ep8u(u0, w0);
        float m01 = x01 + xr1 + ep8u(u0, w1);
        float m10 = x10 + xr0 + ep8u(u1, w0);
        float m11 = x11 + xr1 + ep8u(u1, w1);
        float m20 = x20 + xr0 + ep8u(u2, w0);
        float m21 = x21 + xr1 + ep8u(u2, w1);
        float m30 = x30 + xr0 + ep8u(u3, w0);
        float m31 = x31 + xr1 + ep8u(u3, w1);
        m00 = (m00 > 0.f) ? m00 : 0.2f * m00;
        m01 = (m01 > 0.f) ? m01 : 0.2f * m01;
        m10 = (m10 > 0.f) ? m10 : 0.2f * m10;
        m11 = (m11 > 0.f) ? m11 : 0.2f * m11;
        m20 = (m20 > 0.f) ? m20 : 0.2f * m20;
        m21 = (m21 > 0.f) ? m21 : 0.2f * m21;
        m30 = (m30 > 0.f) ? m30 : 0.2f * m30;
        m31 = (m31 > 0.f) ? m31 : 0.2f * m31;
        float p0 = fmaf(m00, attv.x, m01 * attv.y);
        float p1 = fmaf(m10, attv.x, m11 * attv.y);
        float p2 = fmaf(m20, attv.x, m21 * attv.y);
        float p3 = fmaf(m30, attv.x, m31 * attv.y);
        p0 = row_reduce16(p0);
        p1 = row_reduce16(p1);
        p2 = row_reduce16(p2);
        p3 = row_reduce16(p3);
        float e0v = __expf(p0), e1v = __expf(p1), e2v = __expf(p2), e3v = __expf(p3);
        if (j + 1 >= cnt) e1v = 0.f;
        if (j + 2 >= cnt) e2v = 0.f;
        if (j + 3 >= cnt) e3v = 0.f;
        if (isA) {
          accA0 = fmaf(e0v, x00, accA0); accA1 = fmaf(e0v, x01, accA1);
          accA0 = fmaf(e1v, x10, accA0); accA1 = fmaf(e1v, x11, accA1);
          accA0 = fmaf(e2v, x20, accA0); accA1 = fmaf(e2v, x21, accA1);
          accA0 = fmaf(e3v, x30, accA0); accA1 = fmaf(e3v, x31, accA1);
          denA += (e0v + e1v) + (e2v + e3v);
        } else {
          accB0 = fmaf(e0v, x00, accB0); accB1 = fmaf(e0v, x01, accB1);
          accB0 = fmaf(e1v, x10, accB0); accB1 = fmaf(e1v, x11, accB1);
          accB0 = fmaf(e2v, x20, accB0); accB1 = fmaf(e2v, x21, accB1);
          accB0 = fmaf(e3v, x30, accB0); accB1 = fmaf(e3v, x31, accB1);
          denB += (e0v + e1v) + (e2v + e3v);
        }
      }
      float invA = 1.f / (denA + 1e-16f);
      float invB = 1.f / (denB + 1e-16f);
      hA0 = accA0 * invA + cbv.x; hA1 = accA1 * invA + cbv.y;
      hB0 = accB0 * invB + cbv.x; hB1 = accB1 * invB + cbv.y;
    } else {
      // rare fallback: pair window exceeds 64 edges -> solo path per node
      float accA0 = 0.f, accA1 = 0.f, denA = 0.f;
      float accB0 = 0.f, accB1 = 0.f, denB = 0.f;
      solo_node(e0A, e1A, l, esrc, xlb, eas4, up_lo(xruA), up_hi(xruA),
                w0, w1, attv, accA0, accA1, denA);
      solo_node(e1A, e1B, l, esrc, xlb, eas4, up_lo(xruB), up_hi(xruB),
                w0, w1, attv, accB0, accB1, denB);
      float invA = 1.f / (denA + 1e-16f);
      float invB = 1.f / (denB + 1e-16f);
      hA0 = accA0 * invA + cbv.x; hA1 = accA1 * invA + cbv.y;
      hB0 = accB0 * invB + cbv.x; hB1 = accB1 * invB + cbv.y;
    }
    // packed bf16 buf writes (one u32 per column pair)
    ((unsigned*)(bufs + (size_t)nA * H_))[l] = pk_bf16(hA0, hA1);
    ((unsigned*)(bufs + (size_t)nB * H_))[l] = pk_bf16(hB0, hB1);
    a1_0 += hA0 + hB0; a1_1 += hA1 + hB1;
    a2_0 = fmaf(hA0, hA0, a2_0); a2_0 = fmaf(hB0, hB0, a2_0);
    a2_1 = fmaf(hA1, hA1, a2_1); a2_1 = fmaf(hB1, hB1, a2_1);
  }
  sA[t] = a1_0; sB[t] = a1_1; sC[t] = a2_0; sD[t] = a2_1;
  __syncthreads();
  if (t < 64) {
    float r1 = sA[t] + sA[t + 64] + sA[t + 128] + sA[t + 192];
    float r2 = sB[t] + sB[t + 64] + sB[t + 128] + sB[t + 192];
    float r3 = sC[t] + sC[t + 64] + sC[t + 128] + sC[t + 192];
    float r4 = sD[t] + sD[t + 64] + sD[t + 128] + sD[t + 192];
    atomicAdd(&ssum[2 * t], r1);
    atomicAdd(&ssum[2 * t + 1], r2);
    atomicAdd(&ssq[2 * t], r3);
    atomicAdd(&ssq[2 * t + 1], r4);
  }
}

// ---------------- pooling with fused layer-2 residual (bf16 buf + bf16 xn) --
__global__ __launch_bounds__(128) void pool_residual(const int* __restrict__ goff,
                                                     const unsigned short* __restrict__ xnb,
                                                     const unsigned short* __restrict__ bufs,
                                                     const float* __restrict__ g,
                                                     const float* __restrict__ beta,
                                                     const float* __restrict__ ssum,
                                                     const float* __restrict__ ssq,
                                                     float rows_inv,
                                                     float* __restrict__ xg) {
  int gr = blockIdx.x;
  int t = threadIdx.x;
  int n0 = goff[gr], n1 = goff[gr + 1];
  float mm = ssum[t] * rows_inv;
  float rr = rsqrtf(ssq[t] * rows_inv - mm * mm + 1e-5f);
  float gg = g[t], bb = beta[t];
  float s = 0.f, mx = -INFINITY;
  for (int n = n0; n < n1; n++) {
    float hv = up_s(bufs[(size_t)n * H_ + t]);
    float w = gg * (hv - mm) * rr + bb;
    w = (w > 0.f) ? w : (__expf(w) - 1.f);
    float v = up_s(xnb[(size_t)n * H_ + t]) + w;
    s += v;
    mx = fmaxf(mx, v);
  }
  float c = (float)(n1 - n0);
  xg[gr * 384 + t] = s / fmaxf(c, 1.f);
  xg[gr * 384 + 128 + t] = (c > 0.f) ? mx : 0.f;
  xg[gr * 384 + 256 + t] = s;
}

// ---------------- t1 GEMM (raw output + colstats) ----------------
__global__ void mlp_gemm1(const float* __restrict__ A, const float* __restrict__ W,
                          const float* __restrict__ b, float* __restrict__ Y, int rows,
                          float* __restrict__ ssum, float* __restrict__ ssq) {
  __shared__ float xs[8][384];
  int t = threadIdx.x;  // 256
  int row0 = blockIdx.x * 8;
  for (int i = t; i < 8 * 384; i += 256) {
    int r = i / 384, k = i % 384;
    int row = row0 + r;
    xs[r][k] = (row < rows) ? A[row * 384 + k] : 0.f;
  }
  __syncthreads();
  float acc[8];
#pragma unroll
  for (int r = 0; r < 8; r++) acc[r] = 0.f;
  for (int k = 0; k < 384; k++) {
    float w = W[k * 256 + t];
#pragma unroll
    for (int r = 0; r < 8; r++) acc[r] = fmaf(xs[r][k], w, acc[r]);
  }
  float bb = b[t];
  float a1 = 0.f, a2 = 0.f;
#pragma unroll
  for (int r = 0; r < 8; r++) {
    int row = row0 + r;
    if (row < rows) {
      float v = acc[r] + bb;
      Y[row * 256 + t] = v;
      a1 += v;
      a2 = fmaf(v, v, a2);
    }
  }
  atomicAdd(&ssum[t], a1);
  atomicAdd(&ssq[t], a2);
}

// ---------------- t2 GEMM with inline BN+relu on input (u1 raw) -------------
__global__ void mlp_gemm2(const float* __restrict__ A,
                          const float* __restrict__ g4, const float* __restrict__ be4,
                          const float* __restrict__ s4, const float* __restrict__ q4,
                          float rinv,
                          const float* __restrict__ W, const float* __restrict__ b,
                          float* __restrict__ Y, int rows,
                          float* __restrict__ ssum, float* __restrict__ ssq) {
  __shared__ float xs[8][256];
  int t = threadIdx.x;  // 128
  int row0 = blockIdx.x * 8;
  for (int i = t; i < 8 * 256; i += 128) {
    int r = i >> 8, k = i & 255;
    int row = row0 + r;
    float v = 0.f;
    if (row < rows) {
      float m = s4[k] * rinv;
      float rs = rsqrtf(q4[k] * rinv - m * m + 1e-5f);
      v = fmaxf(g4[k] * (A[row * 256 + k] - m) * rs + be4[k], 0.f);
    }
    xs[r][k] = v;
  }
  __syncthreads();
  float acc[8];
#pragma unroll
  for (int r = 0; r < 8; r++) acc[r] = 0.f;
  for (int k = 0; k < 256; k++) {
    float w = W[k * 128 + t];
#pragma unroll
    for (int r = 0; r < 8; r++) acc[r] = fmaf(xs[r][k], w, acc[r]);
  }
  float bb = b[t];
  float a1 = 0.f, a2 = 0.f;
#pragma unroll
  for (int r = 0; r < 8; r++) {
    int row = row0 + r;
    if (row < rows) {
      float v = acc[r] + bb;
      Y[row * 128 + t] = v;
      a1 += v;
      a2 = fmaf(v, v, a2);
    }
  }
  atomicAdd(&ssum[t], a1);
  atomicAdd(&ssq[t], a2);
}

// ---------------- head with inline BN+relu on input (u2 raw) ----------------
__global__ __launch_bounds__(64) void head_kernel(const float* __restrict__ u,
                                                  const float* __restrict__ g5,
                                                  const float* __restrict__ be5,
                                                  const float* __restrict__ s5,
                                                  const float* __restrict__ q5,
                                                  float rinv,
                                                  const float* __restrict__ W,
                                                  const float* __restrict__ b,
                                                  float* __restrict__ out) {
  __shared__ float row[128];
  int gblk = blockIdx.x;
  int t = threadIdx.x;
#pragma unroll
  for (int h = 0; h < 2; h++) {
    int c = t + h * 64;
    float m = s5[c] * rinv;
    float rs = rsqrtf(q5[c] * rinv - m * m + 1e-5f);
    float v = g5[c] * (u[gblk * 128 + c] - m) * rs + be5[c];
    row[c] = fmaxf(v, 0.f);
  }
  __syncthreads();
  if (t < 12) {
    float acc = b[t];
    for (int k = 0; k < 128; k++) acc = fmaf(row[k], W[k * 12 + t], acc);
    out[gblk * 12 + t] = 1.f / (1.f + expf(-acc));
  }
}

// ---------------- launcher ----------------
extern "C" void kernel_launch(void* const* d_in, const int* in_sizes, int n_in, void* d_out,
                              int out_size, void* d_ws, size_t ws_size, hipStream_t stream) {
  (void)in_sizes; (void)n_in; (void)out_size; (void)ws_size;
  const float* x       = (const float*)d_in[0];
  const int*   ei      = (const int*)d_in[1];
  const float* ea      = (const float*)d_in[2];
  const int*   batch   = (const int*)d_in[3];
  const float* in_W    = (const float*)d_in[4];
  const float* in_b    = (const float*)d_in[5];
  const float* in_g    = (const float*)d_in[6];
  const float* in_beta = (const float*)d_in[7];
  const float* Wl      = (const float*)d_in[8];
  const float* Wr      = (const float*)d_in[9];
  const float* We      = (const float*)d_in[10];
  const float* att     = (const float*)d_in[11];
  const float* conv_b  = (const float*)d_in[12];
  const float* bn_g    = (const float*)d_in[13];
  const float* bn_b    = (const float*)d_in[14];
  const float* t1_W    = (const float*)d_in[15];
  const float* t1_b    = (const float*)d_in[16];
  const float* t1_g    = (const float*)d_in[17];
  const float* t1_beta = (const float*)d_in[18];
  const float* t2_W    = (const float*)d_in[19];
  const float* t2_b    = (const float*)d_in[20];
  const float* t2_g    = (const float*)d_in[21];
  const float* t2_beta = (const float*)d_in[22];
  const float* head_W  = (const float*)d_in[23];
  const float* head_b  = (const float*)d_in[24];
  float* out = (float*)d_out;

  float* p = (float*)d_ws;
  float* xn    = p; p += N_ * H_;   // used as bf16 (half occupied)
  float* buf   = p; p += N_ * H_;   // used as bf16 (half occupied)
  float* xg    = p; p += G_ * 384;
  float* u1    = p; p += G_ * 256;
  float* u2    = p; p += G_ * 128;
  float* sstat = p; p += 6 * 512;   // zeroed region starts here
  int* ip = (int*)p;
  int* deg    = ip; ip += N_;       // contiguous with sstat (one memset)
  int* pref   = ip; ip += 64;       // scan publish flags (zero-init sentinel)
  int* eoff   = ip; ip += N_ + 1;
  int* cursor = ip; ip += N_;
  int* goff   = ip; ip += G_ + 1;
  int* esrc   = ip; ip += E_;
  unsigned* up = (unsigned*)ip;
  unsigned* xlb  = up; up += (size_t)N_ * 64;
  unsigned* xrb  = up; up += (size_t)N_ * 64;
  unsigned* easb = up; up += (size_t)E_ * 4;
  unsigned short* wpack = (unsigned short*)up; up += 3 * 32768 / 2;
  unsigned short* bufs = (unsigned short*)buf;
  unsigned short* xnb = (unsigned short*)xn;

#define SSUM(s) (sstat + (s) * 512)
#define SSQ(s)  (sstat + (s) * 512 + 256)

  // single zeroing memset: sstat (12 KB) | deg (200 KB) | pref (256 B)
  hipMemsetAsync(sstat, 0, (size_t)(6 * 512 + N_ + 64) * sizeof(int), stream);

  // prep: hist + goff + pack_weights + in_gemm (stats -> stage 0)
  prep_kernel<<<HIST_B + GOFF_B + PACK_B + INGEMM_B, 256, 0, stream>>>(
      ei, batch, Wl, Wr, x, in_W, in_b, deg, goff, wpack, bufs, SSUM(0), SSQ(0));

  // CSR: single-pass scan + scatter
  scan_onepass<<<49, 1024, 0, stream>>>(deg, eoff, cursor, pref, N_);
  edge_scatter<<<(E_ + 255) / 256, 256, 0, stream>>>(ei, ea, cursor, esrc, easb);

  // ---- 3 GATv2 layers (conv stats of layer l -> stage l+1) ----
  const float rnInv = 1.f / N_;
  for (int l = 0; l < 3; l++) {
    if (l == 0) {
      gemm_mfma<1><<<782, 256, 0, stream>>>(xnb, bufs, in_g, in_beta, SSUM(0), SSQ(0), rnInv,
                                            wpack + (size_t)l * 32768, xlb, xrb);
    } else {
      gemm_mfma<2><<<782, 256, 0, stream>>>(xnb, bufs, bn_g + (l - 1) * H_, bn_b + (l - 1) * H_,
                                            SSUM(l), SSQ(l), rnInv,
                                            wpack + (size_t)l * 32768, xlb, xrb);
    }
    agg_csr<<<2048, 256, 0, stream>>>(eoff, esrc, easb, We + l * 8 * H_, att + l * H_,
                                      xlb, xrb, conv_b + l * H_, bufs, SSUM(l + 1), SSQ(l + 1));
  }

  // ---- pooling with fused layer-2 residual (stage 3 stats) ----
  pool_residual<<<G_, 128, 0, stream>>>(goff, xnb, bufs, bn_g + 2 * H_, bn_b + 2 * H_,
                                        SSUM(3), SSQ(3), rnInv, xg);

  // ---- t1 (raw + stats 4), t2 (inline BN of u1, raw + stats 5), head ----
  const float rgInv = 1.f / G_;
  mlp_gemm1<<<G_ / 8, 256, 0, stream>>>(xg, t1_W, t1_b, u1, G_, SSUM(4), SSQ(4));
  mlp_gemm2<<<G_ / 8, 128, 0, stream>>>(u1, t1_g, t1_beta, SSUM(4), SSQ(4), rgInv,
                                        t2_W, t2_b, u2, G_, SSUM(5), SSQ(5));
  head_kernel<<<G_, 64, 0, stream>>>(u2, t2_g, t2_beta, SSUM(5), SSQ(5), rgInv,
                                     head_W, head_b, out);
#undef SSUM
#undef SSQ
}